// Round 1
// baseline (1722.045 us; speedup 1.0000x reference)
//
#include <hip/hip_runtime.h>
#include <math.h>

#define KNB 20

// ---------------------------------------------------------------------------
// c_q[n] = bq[n] + sum_j Wq[n, 128+j] * cos(b_t[j])   (src_time is constant)
// ---------------------------------------------------------------------------
__global__ __launch_bounds__(256) void cq_kernel(const float* __restrict__ Wq,
                                                 const float* __restrict__ bq,
                                                 const float* __restrict__ b_t,
                                                 float* __restrict__ c_q) {
    int n = threadIdx.x;  // 256 threads, 1 block
    float s = bq[n];
    for (int j = 0; j < 128; j++) s = fmaf(Wq[n * 256 + 128 + j], cosf(b_t[j]), s);
    c_q[n] = s;
}

// ---------------------------------------------------------------------------
// src_feat[b] = node_features[src[b]] + memory[src[b]]
// ---------------------------------------------------------------------------
__global__ __launch_bounds__(256) void srcfeat_kernel(const float* __restrict__ nf,
                                                      const float* __restrict__ mem,
                                                      const int* __restrict__ src,
                                                      float* __restrict__ sf, int total) {
    int idx = blockIdx.x * 256 + threadIdx.x;  // over B*32 float4 slots
    if (idx >= total) return;
    int b = idx >> 5, c4 = idx & 31;
    size_t s = (size_t)src[b];
    float4 a = ((const float4*)(nf + s * 128))[c4];
    float4 m = ((const float4*)(mem + s * 128))[c4];
    float4 r = make_float4(a.x + m.x, a.y + m.y, a.z + m.z, a.w + m.w);
    ((float4*)(sf + (size_t)b * 128))[c4] = r;
}

// ---------------------------------------------------------------------------
// Generic fp32 tiled GEMM: C[m,n] = act( rowscale[m]*(A@W + bias) + Cin )
//   A: [M x K], row-major, leading dim lda
//   W element (n,k) at W[n*sWn + k*sWk]   (supports W^T and W layouts)
//   grid = (M/64, N/64), block = 256.  M,N multiples of 64, K multiple of 32.
// ---------------------------------------------------------------------------
__global__ __launch_bounds__(256) void gemm_f32(
    const float* __restrict__ A, int lda,
    const float* __restrict__ W, int sWn, int sWk,
    const float* __restrict__ bias,
    const float* __restrict__ rowscale,
    const float* __restrict__ Cin,
    float* __restrict__ C, int ldc,
    int K, int act) {
    __shared__ float As[32][68];
    __shared__ float Bs[32][68];
    int m0 = blockIdx.x * 64, n0 = blockIdx.y * 64;
    int tid = threadIdx.x;
    int tx = tid & 15, ty = tid >> 4;
    float acc[4][4] = {};

    for (int k0 = 0; k0 < K; k0 += 32) {
        // A tile 64x32, transposed into LDS
        for (int f = tid; f < 512; f += 256) {
            int r = f >> 3, c4 = f & 7;
            float4 a4 = *(const float4*)&A[(size_t)(m0 + r) * lda + k0 + c4 * 4];
            As[c4 * 4 + 0][r] = a4.x;
            As[c4 * 4 + 1][r] = a4.y;
            As[c4 * 4 + 2][r] = a4.z;
            As[c4 * 4 + 3][r] = a4.w;
        }
        // W tile 64(n) x 32(k) -> Bs[k][n]
        if (sWk == 1) {
            for (int f = tid; f < 512; f += 256) {
                int n = f >> 3, c4 = f & 7;
                float4 w4 = *(const float4*)&W[(size_t)(n0 + n) * sWn + k0 + c4 * 4];
                Bs[c4 * 4 + 0][n] = w4.x;
                Bs[c4 * 4 + 1][n] = w4.y;
                Bs[c4 * 4 + 2][n] = w4.z;
                Bs[c4 * 4 + 3][n] = w4.w;
            }
        } else {  // sWn == 1, contiguous in n
            for (int f = tid; f < 512; f += 256) {
                int c = f >> 4, n4 = f & 15;
                float4 w4 = *(const float4*)&W[(size_t)(k0 + c) * sWk + n0 + n4 * 4];
                *(float4*)&Bs[c][n4 * 4] = w4;
            }
        }
        __syncthreads();
#pragma unroll
        for (int kk = 0; kk < 32; kk++) {
            float4 av = *(const float4*)&As[kk][ty * 4];
            float4 bv = *(const float4*)&Bs[kk][tx * 4];
            float va[4] = {av.x, av.y, av.z, av.w};
            float vb[4] = {bv.x, bv.y, bv.z, bv.w};
#pragma unroll
            for (int i = 0; i < 4; i++)
#pragma unroll
                for (int j = 0; j < 4; j++) acc[i][j] = fmaf(va[i], vb[j], acc[i][j]);
        }
        __syncthreads();
    }

    int col0 = n0 + tx * 4;
#pragma unroll
    for (int i = 0; i < 4; i++) {
        int row = m0 + ty * 4 + i;
        float scale = rowscale ? rowscale[row] : 1.f;
        float o[4];
#pragma unroll
        for (int j = 0; j < 4; j++) {
            float v = acc[i][j];
            if (bias) v += bias[col0 + j];
            v *= scale;
            if (Cin) v += Cin[(size_t)row * ldc + col0 + j];
            if (act == 1) v = fmaxf(v, 0.f);
            o[j] = v;
        }
        *(float4*)&C[(size_t)row * ldc + col0] = make_float4(o[0], o[1], o[2], o[3]);
    }
}

// ---------------------------------------------------------------------------
// Fused attention: one block per batch row.
//  - build keyv[20][384] in LDS (gather nf+mem | cos time-encode | gather ef)
//  - scores_hk = (qk_h . keyv_k)/sqrt(128), masked (TGN slot-0 trick)
//  - softmax over K per head
//  - ctxkv_h = sum_k attn_hk * keyv_k  -> [B,768]
// ---------------------------------------------------------------------------
__global__ __launch_bounds__(256) void attn_kernel(
    const float* __restrict__ nf, const float* __restrict__ ef,
    const float* __restrict__ mem,
    const float* __restrict__ w_t, const float* __restrict__ b_t,
    const float* __restrict__ qk,          // [B, 768]
    const float* __restrict__ timestamps,  // [B]
    const float* __restrict__ edge_times,  // [B, K]
    const int* __restrict__ neighbors,     // [B, K]
    const int* __restrict__ edge_idxs,     // [B, K]
    float* __restrict__ ctxkv,             // [B, 768]
    float* __restrict__ validb)            // [B]
{
    int b = blockIdx.x;
    int tid = threadIdx.x;
    __shared__ float kv[KNB][384];
    __shared__ float qks[768];
    __shared__ float wts[128], bts[128];
    __shared__ int nbs[KNB];
    __shared__ float scores_s[2][KNB];
    __shared__ float attn_s[2][KNB];
    __shared__ int inval_s;

    for (int i = tid; i < 192; i += 256)
        ((float4*)qks)[i] = ((const float4*)(qk + (size_t)b * 768))[i];
    if (tid < 32)
        ((float4*)wts)[tid] = ((const float4*)w_t)[tid];
    else if (tid < 64)
        ((float4*)bts)[tid - 32] = ((const float4*)b_t)[tid - 32];
    if (tid < KNB) nbs[tid] = neighbors[(size_t)b * KNB + tid];
    __syncthreads();

    if (tid == 0) {
        int inv = 1;
        for (int k = 0; k < KNB; k++)
            if (nbs[k] != 0) { inv = 0; break; }
        inval_s = inv;
        validb[b] = inv ? 0.f : 1.f;
    }
    float tb = timestamps[b];

    // build keyv rows: 20 rows x 96 float4 slots
    for (int idx = tid; idx < KNB * 96; idx += 256) {
        int k = idx / 96, c4 = idx % 96;
        if (c4 < 32) {
            size_t nb = (size_t)nbs[k];
            float4 a = ((const float4*)(nf + nb * 128))[c4];
            float4 m = ((const float4*)(mem + nb * 128))[c4];
            *(float4*)&kv[k][c4 * 4] =
                make_float4(a.x + m.x, a.y + m.y, a.z + m.z, a.w + m.w);
        } else if (c4 < 64) {
            int j = (c4 - 32) * 4;
            float delta = tb - edge_times[(size_t)b * KNB + k];
#pragma unroll
            for (int jj = 0; jj < 4; jj++)
                kv[k][128 + j + jj] = cosf(fmaf(delta, wts[j + jj], bts[j + jj]));
        } else {
            size_t e = (size_t)edge_idxs[(size_t)b * KNB + k];
            float4 w = ((const float4*)(ef + e * 128))[c4 - 64];
            *(float4*)&kv[k][256 + (c4 - 64) * 4] = w;
        }
    }
    __syncthreads();

    // scores: 40 dot products of length 384, one per (h,k), wave-parallel
    int wave = tid >> 6, lane = tid & 63;
    for (int p = wave; p < 2 * KNB; p += 4) {
        int h = p / KNB, k = p % KNB;
        const float* qh = qks + h * 384;
        float s = 0.f;
#pragma unroll
        for (int i = 0; i < 6; i++) {
            int j = lane + 64 * i;
            s = fmaf(qh[j], kv[k][j], s);
        }
#pragma unroll
        for (int off = 32; off > 0; off >>= 1) s += __shfl_down(s, off);
        if (lane == 0) {
            bool masked = (nbs[k] == 0) && !(k == 0 && inval_s);
            scores_s[h][k] = masked ? -1e30f : s * 0.08838834764831845f;  // 1/sqrt(128)
        }
    }
    __syncthreads();

    // softmax per head (tiny: 2 threads, 20 elems each)
    if (tid < 2) {
        int h = tid;
        float mx = -3.0e38f;
        for (int k = 0; k < KNB; k++) mx = fmaxf(mx, scores_s[h][k]);
        float ev[KNB];
        float sum = 0.f;
        for (int k = 0; k < KNB; k++) {
            ev[k] = expf(scores_s[h][k] - mx);
            sum += ev[k];
        }
        float inv = 1.f / sum;
        for (int k = 0; k < KNB; k++) attn_s[h][k] = ev[k] * inv;
    }
    __syncthreads();

    // ctxkv[h*384+j] = sum_k attn[h][k] * kv[k][j]
    for (int idx = tid; idx < 768; idx += 256) {
        int h = idx / 384, j = idx % 384;
        float s = 0.f;
#pragma unroll
        for (int k = 0; k < KNB; k++) s = fmaf(attn_s[h][k], kv[k][j], s);
        ctxkv[(size_t)b * 768 + idx] = s;
    }
}

// ---------------------------------------------------------------------------
extern "C" void kernel_launch(void* const* d_in, const int* in_sizes, int n_in,
                              void* d_out, int out_size, void* d_ws, size_t ws_size,
                              hipStream_t stream) {
    (void)n_in; (void)out_size; (void)ws_size;
    const float* nf  = (const float*)d_in[0];
    const float* ef  = (const float*)d_in[1];
    const float* mem = (const float*)d_in[2];
    const float* w_t = (const float*)d_in[3];
    const float* b_t = (const float*)d_in[4];
    const float* Wq  = (const float*)d_in[5];
    const float* bq  = (const float*)d_in[6];
    const float* Wk  = (const float*)d_in[7];
    // d_in[8] = bk: dropped — constant shift across k, softmax-invariant
    const float* Wv  = (const float*)d_in[9];
    const float* bv  = (const float*)d_in[10];
    const float* Wo  = (const float*)d_in[11];
    const float* bo  = (const float*)d_in[12];
    const float* W1  = (const float*)d_in[13];
    const float* b1  = (const float*)d_in[14];
    const float* W2  = (const float*)d_in[15];
    const float* b2  = (const float*)d_in[16];
    const float* ts  = (const float*)d_in[17];
    const float* ets = (const float*)d_in[18];
    const int* src   = (const int*)d_in[19];
    const int* nbrs  = (const int*)d_in[20];
    const int* eidx  = (const int*)d_in[21];
    float* out = (float*)d_out;

    int B = in_sizes[17];           // 32768
    size_t Bz = (size_t)B;
    float* ws = (float*)d_ws;

    float* sf     = ws;                  // [B,128]
    float* qbuf   = sf + Bz * 128;       // [B,256]  (q, later ctx)
    float* qkbuf  = qbuf + Bz * 256;     // [B,768]  (qk; later outbuf/h1buf)
    float* ckv    = qkbuf + Bz * 768;    // [B,768]
    float* validb = ckv + Bz * 768;      // [B]
    float* cq     = validb + Bz;         // [256]
    float* outbuf = qkbuf;               // [B,256] reuse (qk dead after attn)
    float* h1buf  = qkbuf + Bz * 256;    // [B,128] reuse

    cq_kernel<<<1, 256, 0, stream>>>(Wq, bq, b_t, cq);
    srcfeat_kernel<<<(B * 32 + 255) / 256, 256, 0, stream>>>(nf, mem, src, sf, B * 32);

    // q = src_feat @ Wq[:, :128]^T + c_q        [B,256]
    gemm_f32<<<dim3(B / 64, 4), 256, 0, stream>>>(sf, 128, Wq, 256, 1, cq,
                                                  nullptr, nullptr, qbuf, 256, 128, 0);
    // qk_h = q_h @ Wk_h                          [B,768]
    for (int h = 0; h < 2; h++)
        gemm_f32<<<dim3(B / 64, 6), 256, 0, stream>>>(qbuf + h * 128, 256,
                                                      Wk + (size_t)h * 128 * 384, 1, 384,
                                                      nullptr, nullptr, nullptr,
                                                      qkbuf + h * 384, 768, 128, 0);
    // fused attention -> ctxkv [B,768], validb [B]
    attn_kernel<<<B, 256, 0, stream>>>(nf, ef, mem, w_t, b_t, qkbuf, ts, ets,
                                       nbrs, eidx, ckv, validb);
    // ctx_h = ctxkv_h @ Wv_h^T + bv_h            [B,256] (into qbuf)
    for (int h = 0; h < 2; h++)
        gemm_f32<<<dim3(B / 64, 2), 256, 0, stream>>>(ckv + h * 384, 768,
                                                      Wv + (size_t)h * 128 * 384, 384, 1,
                                                      bv + h * 128, nullptr, nullptr,
                                                      qbuf + h * 128, 256, 384, 0);
    // out = valid * (ctx @ Wo^T + bo)            [B,256]
    gemm_f32<<<dim3(B / 64, 4), 256, 0, stream>>>(qbuf, 256, Wo, 256, 1, bo,
                                                  validb, nullptr, outbuf, 256, 256, 0);
    // h1 = relu(out @ W1[:, :256]^T + b1 + src_feat @ W1[:, 256:]^T)
    gemm_f32<<<dim3(B / 64, 2), 256, 0, stream>>>(outbuf, 256, W1, 384, 1, b1,
                                                  nullptr, nullptr, h1buf, 128, 256, 0);
    gemm_f32<<<dim3(B / 64, 2), 256, 0, stream>>>(sf, 128, W1 + 256, 384, 1, nullptr,
                                                  nullptr, h1buf, h1buf, 128, 128, 1);
    // out = h1 @ W2^T + b2                       [B,128]
    gemm_f32<<<dim3(B / 64, 2), 256, 0, stream>>>(h1buf, 128, W2, 128, 1, b2,
                                                  nullptr, nullptr, out, 128, 128, 0);
}